// Round 13
// baseline (176.727 us; speedup 1.0000x reference)
//
#include <hip/hip_runtime.h>
#include <math.h>

#define F_IN 165
#define HID 16
#define NPB 256         // nodes per bucket
#define NPB_BITS 8
#define MAXB 512        // padded bucket-array size (nbuck=391)
#define CHUNK 4096      // edges per chunk (k_cnt / k_binscatter block)
#define EPT 16          // CHUNK/256
#define SSTAGE 12288    // sortnode LDS staging capacity (avg bucket ~8192)

__device__ __forceinline__ unsigned pk_bf16(float lo, float hi) {
    unsigned a = __float_as_uint(lo), b = __float_as_uint(hi);
    a += 0x7FFF + ((a >> 16) & 1);       // RNE
    b += 0x7FFF + ((b >> 16) & 1);
    return (a >> 16) | (b & 0xFFFF0000u);
}
#define BF_LO(w) __uint_as_float((w) << 16)
#define BF_HI(w) __uint_as_float((w) & 0xFFFF0000u)

// ---- per-chunk bucket histogram -> cbM[chunk][MAXB] (coalesced row) ----
__global__ __launch_bounds__(256) void k_cnt(const int* __restrict__ dst,
                                             int* __restrict__ cbM, int E) {
    __shared__ int h[MAXB];
    int t = threadIdx.x;
    for (int i = t; i < MAXB; i += 256) h[i] = 0;
    __syncthreads();
    int e0 = blockIdx.x * CHUNK;
    int n = min(CHUNK, E - e0);
    for (int k = t; k < n; k += 256)
        atomicAdd(&h[dst[e0 + k] >> NPB_BITS], 1);
    __syncthreads();
    for (int i = t; i < MAXB; i += 256)
        cbM[blockIdx.x * MAXB + i] = h[i];
}

// ---- per-bucket column scan (in place): cbM[c][b] -> excl prefix; btot[b] ----
__global__ __launch_bounds__(256) void k_colscan(int* __restrict__ cbM,
                                                 int* __restrict__ btot, int NB) {
    __shared__ int ps[256];
    int b = blockIdx.x, t = threadIdx.x;
    int i0 = t * 4;
    int v[4];
    int s = 0;
#pragma unroll
    for (int u = 0; u < 4; ++u) {
        int c = i0 + u;
        v[u] = (c < NB) ? cbM[c * MAXB + b] : 0;
        s += v[u];
    }
    ps[t] = s;
    __syncthreads();
    for (int off = 1; off < 256; off <<= 1) {
        int a = (t >= off) ? ps[t - off] : 0;
        __syncthreads();
        ps[t] += a;
        __syncthreads();
    }
    int run = ps[t] - s;
#pragma unroll
    for (int u = 0; u < 4; ++u) {
        int c = i0 + u;
        if (c < NB) cbM[c * MAXB + b] = run;
        run += v[u];
    }
    if (t == 255) btot[b] = ps[255];
}

// ---- single-block exclusive scan of bucket totals -> bofs ----
__global__ __launch_bounds__(256) void k_bscan(const int* __restrict__ btot,
                                               int* __restrict__ bofs,
                                               int* __restrict__ rowptr,
                                               int nbuck, int N) {
    __shared__ int ps[256];
    int t = threadIdx.x;
    int i0 = 2 * t, i1 = 2 * t + 1;
    int c0 = (i0 < nbuck) ? btot[i0] : 0;
    int c1 = (i1 < nbuck) ? btot[i1] : 0;
    int s = c0 + c1;
    ps[t] = s;
    __syncthreads();
    for (int off = 1; off < 256; off <<= 1) {
        int a = (t >= off) ? ps[t - off] : 0;
        __syncthreads();
        ps[t] += a;
        __syncthreads();
    }
    int excl = ps[t] - s;
    if (i0 < nbuck) bofs[i0] = excl;
    if (i1 < nbuck) bofs[i1] = excl + c0;
    if (t == 255) { bofs[nbuck] = ps[255]; rowptr[N] = ps[255]; }
}

// ---- counting-sort edges into bucket-major order, packed (src<<8)|dstlow ----
// ZERO global atomics: write base = bofs[b] + cbM[me][b] (deterministic).
__global__ __launch_bounds__(256) void k_binscatter(const int* __restrict__ src,
                                                    const int* __restrict__ dst,
                                                    const int* __restrict__ cbM,
                                                    const int* __restrict__ bofs,
                                                    unsigned* __restrict__ sedge,
                                                    int E, int nbuck) {
    __shared__ int hist[MAXB];
    __shared__ int lofs[MAXB];
    __shared__ int dlt[MAXB];       // (bofs[b] + cbM[me][b]) - lofs[b]
    __shared__ int ps[256];
    __shared__ uint2 stg[CHUNK];
    int t = threadIdx.x;
    int me = blockIdx.x;
    int e0 = me * CHUNK;
    int n = min(CHUNK, E - e0);

    int d[EPT], sv[EPT], rk[EPT];
#pragma unroll
    for (int u = 0; u < EPT; ++u) {
        int k = t + u * 256;
        d[u]  = (k < n) ? dst[e0 + k] : -1;
        sv[u] = (k < n) ? src[e0 + k] : 0;
    }
    for (int i = t; i < MAXB; i += 256) hist[i] = 0;
    __syncthreads();
#pragma unroll
    for (int u = 0; u < EPT; ++u)
        if (d[u] >= 0) rk[u] = atomicAdd(&hist[d[u] >> NPB_BITS], 1);
    __syncthreads();

    // block exclusive scan of hist (512 entries, 2 per thread)
    int base = t * 2;
    int h0 = hist[base], h1 = hist[base + 1];
    int s = h0 + h1;
    ps[t] = s;
    __syncthreads();
    for (int off = 1; off < 256; off <<= 1) {
        int a = (t >= off) ? ps[t - off] : 0;
        __syncthreads();
        ps[t] += a;
        __syncthreads();
    }
    int excl = ps[t] - s;
    lofs[base] = excl;
    lofs[base + 1] = excl + h0;
    __syncthreads();
    for (int i = t; i < nbuck; i += 256)
        dlt[i] = bofs[i] + cbM[me * MAXB + i] - lofs[i];
    __syncthreads();

    // place into bucket-major staging at r = lofs[b] + rank; addr fused in .y
#pragma unroll
    for (int u = 0; u < EPT; ++u) {
        if (d[u] < 0) continue;
        int b = d[u] >> NPB_BITS;
        int r = lofs[b] + rk[u];
        stg[r] = make_uint2(((unsigned)sv[u] << NPB_BITS) | (unsigned)(d[u] & (NPB - 1)),
                            (unsigned)(dlt[b] + r));
    }
    __syncthreads();

    // write-out: stride-1 LDS read pair + store (depth-1 chain)
    for (int r = t; r < n; r += 256) {
        uint2 v = stg[r];
        sedge[v.y] = v.x;
    }
}

// ---- within-bucket: node histogram (LDS) -> rowptr + dinv + sorted csr ----
__global__ __launch_bounds__(256) void k_sortnode(const int* __restrict__ bofs,
                                                  const unsigned* __restrict__ sedge,
                                                  int* __restrict__ csr,
                                                  int* __restrict__ rowptr,
                                                  float* __restrict__ dinv, int N) {
    __shared__ int hist[256];
    __shared__ int ps[256];
    __shared__ int lcur[256];
    __shared__ int stage[SSTAGE];
    int b = blockIdx.x, t = threadIdx.x;
    int base = bofs[b];
    int n = bofs[b + 1] - base;
    hist[t] = 0;
    __syncthreads();
    for (int k = t; k < n; k += 256)
        atomicAdd(&hist[sedge[base + k] & (NPB - 1)], 1);
    __syncthreads();
    int c = hist[t];
    ps[t] = c;
    __syncthreads();
    for (int off = 1; off < 256; off <<= 1) {
        int a = (t >= off) ? ps[t - off] : 0;
        __syncthreads();
        ps[t] += a;
        __syncthreads();
    }
    int excl = ps[t] - c;
    int node = b * NPB + t;
    if (node < N) {
        rowptr[node] = base + excl;
        dinv[node] = rsqrtf((float)c + 1.0f);
    }
    lcur[t] = excl;
    __syncthreads();
    bool staged = (n <= SSTAGE);
    for (int k = t; k < n; k += 256) {
        unsigned p = sedge[base + k];
        int d = p & (NPB - 1);
        int pos = atomicAdd(&lcur[d], 1);
        int sv = (int)(p >> NPB_BITS);
        if (staged) stage[pos] = sv;
        else        csr[base + pos] = sv;
    }
    __syncthreads();
    if (staged) {
        for (int k = t; k < n; k += 256) csr[base + k] = stage[k];
    }
}

// ---- g1 = bf16((x @ W1) * dinv[row]) ----
// One thread per row, all 16 cols. W1 address is lane-invariant -> compiler
// emits s_load (SMEM path): zero LDS, zero DS-pipe traffic. 16 independent
// FMA chains give ILP; x row read as float4 with alignment peel.
#define FMAROW(vv, kk)                                                  \
    {                                                                   \
        const float* w = W1 + (kk) * HID;                               \
        _Pragma("unroll")                                               \
        for (int c = 0; c < HID; ++c) acc[c] = fmaf((vv), w[c], acc[c]);\
    }

__global__ __launch_bounds__(64) void k_gemm1(const float* __restrict__ x,
                                              const float* __restrict__ W1,
                                              const float* __restrict__ dinv,
                                              unsigned* __restrict__ g1, int N) {
    int row = blockIdx.x * 64 + threadIdx.x;
    if (row >= N) return;
    const float* xr = x + (long long)row * F_IN;
    float acc[HID];
#pragma unroll
    for (int c = 0; c < HID; ++c) acc[c] = 0.f;

    int p = (4 - (row & 3)) & 3;   // dwords to 16B boundary
    for (int k = 0; k < p; ++k) { float v = xr[k]; FMAROW(v, k); }

    const float4* xr4 = (const float4*)(xr + p);
    int n4 = (F_IN - p) >> 2;      // 40 or 41
    for (int q = 0; q < n4; ++q) {
        float4 v = xr4[q];
        int kb = p + q * 4;
        FMAROW(v.x, kb + 0)
        FMAROW(v.y, kb + 1)
        FMAROW(v.z, kb + 2)
        FMAROW(v.w, kb + 3)
    }
    for (int k = p + n4 * 4; k < F_IN; ++k) { float v = xr[k]; FMAROW(v, k); }

    float di = dinv[row];
    unsigned* o = g1 + (long long)row * 8;
    uint4 o0 = make_uint4(pk_bf16(acc[0] * di, acc[1] * di),
                          pk_bf16(acc[2] * di, acc[3] * di),
                          pk_bf16(acc[4] * di, acc[5] * di),
                          pk_bf16(acc[6] * di, acc[7] * di));
    uint4 o1 = make_uint4(pk_bf16(acc[8] * di, acc[9] * di),
                          pk_bf16(acc[10] * di, acc[11] * di),
                          pk_bf16(acc[12] * di, acc[13] * di),
                          pk_bf16(acc[14] * di, acc[15] * di));
    *(uint4*)(o)     = o0;
    *(uint4*)(o + 4) = o1;
}

// ---- layer-1 CSR gather (bf16 rows), fp32 accum, fused bias/relu/W2 -> g2 ----
__global__ __launch_bounds__(256) void k_agg1(const int* __restrict__ rowptr,
                                              const int* __restrict__ csr,
                                              const unsigned* __restrict__ g1,
                                              const float* __restrict__ dinv,
                                              const float* __restrict__ b1,
                                              const float* __restrict__ W2,
                                              float* __restrict__ g2, int N) {
    int gid = blockIdx.x * 256 + threadIdx.x;
    int i = gid >> 3;
    int j = gid & 7;
    if (i >= N) return;
    int e0 = rowptr[i], e1 = rowptr[i + 1];
    unsigned w0 = g1[i * 8 + j];           // self-loop term
    float a0 = BF_LO(w0), a1 = BF_HI(w0);
    int e = e0;
    for (; e + 8 <= e1; e += 8) {
        int s0 = csr[e],     s1 = csr[e + 1], s2 = csr[e + 2], s3 = csr[e + 3];
        int s4 = csr[e + 4], s5 = csr[e + 5], s6 = csr[e + 6], s7 = csr[e + 7];
        unsigned u0 = g1[s0 * 8 + j], u1 = g1[s1 * 8 + j];
        unsigned u2 = g1[s2 * 8 + j], u3 = g1[s3 * 8 + j];
        unsigned u4 = g1[s4 * 8 + j], u5 = g1[s5 * 8 + j];
        unsigned u6 = g1[s6 * 8 + j], u7 = g1[s7 * 8 + j];
        a0 += ((BF_LO(u0) + BF_LO(u1)) + (BF_LO(u2) + BF_LO(u3))) +
              ((BF_LO(u4) + BF_LO(u5)) + (BF_LO(u6) + BF_LO(u7)));
        a1 += ((BF_HI(u0) + BF_HI(u1)) + (BF_HI(u2) + BF_HI(u3))) +
              ((BF_HI(u4) + BF_HI(u5)) + (BF_HI(u6) + BF_HI(u7)));
    }
    for (; e < e1; ++e) {
        unsigned u = g1[csr[e] * 8 + j];
        a0 += BF_LO(u);
        a1 += BF_HI(u);
    }
    float di = dinv[i];
    float v0 = fmaf(a0, di, b1[2 * j]);     v0 = v0 > 0.f ? v0 : 0.f;
    float v1 = fmaf(a1, di, b1[2 * j + 1]); v1 = v1 > 0.f ? v1 : 0.f;
    float4 w = ((const float4*)W2)[j];      // W2[2j][0..1], W2[2j+1][0..1]
    float c0 = fmaf(v1, w.z, v0 * w.x);
    float c1 = fmaf(v1, w.w, v0 * w.y);
    for (int off = 4; off; off >>= 1) {
        c0 += __shfl_xor(c0, off, 8);
        c1 += __shfl_xor(c1, off, 8);
    }
    if (j == 0) ((float2*)g2)[i] = make_float2(c0 * di, c1 * di);
}

// ---- layer-2 CSR gather + fused log_softmax -> out (4 lanes/node) ----
__global__ __launch_bounds__(256) void k_agg2(const int* __restrict__ rowptr,
                                              const int* __restrict__ csr,
                                              const float* __restrict__ g2,
                                              const float* __restrict__ dinv,
                                              const float* __restrict__ b2,
                                              float* __restrict__ out, int N) {
    int gid = blockIdx.x * 256 + threadIdx.x;
    int i = gid >> 2;
    int l = gid & 3;
    if (i >= N) return;
    int e0 = rowptr[i], e1 = rowptr[i + 1];
    float a0 = 0.f, a1 = 0.f;
    int e = e0 + l;
    for (; e + 4 < e1; e += 8) {
        int s0 = csr[e], s1 = csr[e + 4];
        float2 u = ((const float2*)g2)[s0];
        float2 w = ((const float2*)g2)[s1];
        a0 += u.x + w.x;
        a1 += u.y + w.y;
    }
    for (; e < e1; e += 4) {
        int s = csr[e];
        float2 u = ((const float2*)g2)[s];
        a0 += u.x;
        a1 += u.y;
    }
    a0 += __shfl_xor(a0, 1, 4); a0 += __shfl_xor(a0, 2, 4);
    a1 += __shfl_xor(a1, 1, 4); a1 += __shfl_xor(a1, 2, 4);
    if (l == 0) {
        float2 self = ((const float2*)g2)[i];
        float di = dinv[i];
        float A = fmaf(a0 + self.x, di, b2[0]);
        float B = fmaf(a1 + self.y, di, b2[1]);
        float m = fmaxf(A, B);
        float lse = m + logf(expf(A - m) + expf(B - m));
        ((float2*)out)[i] = make_float2(A - lse, B - lse);
    }
}

extern "C" void kernel_launch(void* const* d_in, const int* in_sizes, int n_in,
                              void* d_out, int out_size, void* d_ws, size_t ws_size,
                              hipStream_t stream) {
    const float* x  = (const float*)d_in[0];
    const int*   ei = (const int*)d_in[1];
    const float* W1 = (const float*)d_in[2];
    const float* b1 = (const float*)d_in[3];
    const float* W2 = (const float*)d_in[4];
    const float* b2 = (const float*)d_in[5];
    float* out = (float*)d_out;

    int N = in_sizes[0] / F_IN;
    int E = in_sizes[1] / 2;
    const int* src = ei;
    const int* dst = ei + E;
    int nbuck = (N + NPB - 1) >> NPB_BITS;
    int NB = (E + CHUNK - 1) / CHUNK;

    int* cbM      = (int*)d_ws;                     // NB*MAXB (counts -> excl offsets)
    int* btot     = cbM + (long long)NB * MAXB;     // MAXB
    int* bofs     = btot + MAXB;                    // MAXB+1
    int* rowptr   = bofs + MAXB + 1;                // N+1
    unsigned* sedge = (unsigned*)(rowptr + N + 1);  // E
    int* csr      = (int*)(sedge + E);              // E
    float* dinv   = (float*)(csr + E);              // N
    unsigned* g1  = (unsigned*)(dinv + N);          // 8N (bf16 rows)
    float* g2     = (float*)(g1 + (long long)8 * N);// 2N

    k_cnt<<<NB, 256, 0, stream>>>(dst, cbM, E);
    k_colscan<<<nbuck, 256, 0, stream>>>(cbM, btot, NB);
    k_bscan<<<1, 256, 0, stream>>>(btot, bofs, rowptr, nbuck, N);
    k_binscatter<<<NB, 256, 0, stream>>>(src, dst, cbM, bofs, sedge, E, nbuck);
    k_sortnode<<<nbuck, 256, 0, stream>>>(bofs, sedge, csr, rowptr, dinv, N);

    k_gemm1<<<(N + 63) / 64, 64, 0, stream>>>(x, W1, dinv, g1, N);

    k_agg1<<<(N * 8 + 255) / 256, 256, 0, stream>>>(rowptr, csr, g1, dinv, b1, W2, g2, N);
    k_agg2<<<(N * 4 + 255) / 256, 256, 0, stream>>>(rowptr, csr, g2, dinv, b2, out, N);
}

// Round 14
// 130.296 us; speedup vs baseline: 1.3563x; 1.3563x over previous
//
#include <hip/hip_runtime.h>
#include <math.h>

#define F_IN 165
#define HID 16
#define NPB 256         // nodes per bucket
#define NPB_BITS 8
#define MAXB 512        // padded bucket-array size (nbuck=391)
#define CHUNK 4096      // edges per chunk (k_cnt / k_binscatter block)
#define EPT 16          // CHUNK/256
#define SSTAGE 12288    // sortnode LDS staging capacity (avg bucket ~8192)

__device__ __forceinline__ unsigned pk_bf16(float lo, float hi) {
    unsigned a = __float_as_uint(lo), b = __float_as_uint(hi);
    a += 0x7FFF + ((a >> 16) & 1);       // RNE
    b += 0x7FFF + ((b >> 16) & 1);
    return (a >> 16) | (b & 0xFFFF0000u);
}
#define BF_LO(w) __uint_as_float((w) << 16)
#define BF_HI(w) __uint_as_float((w) & 0xFFFF0000u)

// ---- per-chunk bucket histogram -> cbM[chunk][MAXB] (coalesced row) ----
__global__ __launch_bounds__(256) void k_cnt(const int* __restrict__ dst,
                                             int* __restrict__ cbM, int E) {
    __shared__ int h[MAXB];
    int t = threadIdx.x;
    for (int i = t; i < MAXB; i += 256) h[i] = 0;
    __syncthreads();
    int e0 = blockIdx.x * CHUNK;
    int n = min(CHUNK, E - e0);
    for (int k = t; k < n; k += 256)
        atomicAdd(&h[dst[e0 + k] >> NPB_BITS], 1);
    __syncthreads();
    for (int i = t; i < MAXB; i += 256)
        cbM[blockIdx.x * MAXB + i] = h[i];
}

// ---- per-bucket column scan (in place): cbM[c][b] -> excl prefix; btot[b] ----
__global__ __launch_bounds__(256) void k_colscan(int* __restrict__ cbM,
                                                 int* __restrict__ btot, int NB) {
    __shared__ int ps[256];
    int b = blockIdx.x, t = threadIdx.x;
    int i0 = t * 4;
    int v[4];
    int s = 0;
#pragma unroll
    for (int u = 0; u < 4; ++u) {
        int c = i0 + u;
        v[u] = (c < NB) ? cbM[c * MAXB + b] : 0;
        s += v[u];
    }
    ps[t] = s;
    __syncthreads();
    for (int off = 1; off < 256; off <<= 1) {
        int a = (t >= off) ? ps[t - off] : 0;
        __syncthreads();
        ps[t] += a;
        __syncthreads();
    }
    int run = ps[t] - s;
#pragma unroll
    for (int u = 0; u < 4; ++u) {
        int c = i0 + u;
        if (c < NB) cbM[c * MAXB + b] = run;
        run += v[u];
    }
    if (t == 255) btot[b] = ps[255];
}

// ---- single-block exclusive scan of bucket totals -> bofs ----
__global__ __launch_bounds__(256) void k_bscan(const int* __restrict__ btot,
                                               int* __restrict__ bofs,
                                               int* __restrict__ rowptr,
                                               int nbuck, int N) {
    __shared__ int ps[256];
    int t = threadIdx.x;
    int i0 = 2 * t, i1 = 2 * t + 1;
    int c0 = (i0 < nbuck) ? btot[i0] : 0;
    int c1 = (i1 < nbuck) ? btot[i1] : 0;
    int s = c0 + c1;
    ps[t] = s;
    __syncthreads();
    for (int off = 1; off < 256; off <<= 1) {
        int a = (t >= off) ? ps[t - off] : 0;
        __syncthreads();
        ps[t] += a;
        __syncthreads();
    }
    int excl = ps[t] - s;
    if (i0 < nbuck) bofs[i0] = excl;
    if (i1 < nbuck) bofs[i1] = excl + c0;
    if (t == 255) { bofs[nbuck] = ps[255]; rowptr[N] = ps[255]; }
}

// ---- counting-sort edges into bucket-major order, packed (src<<8)|dstlow ----
// ZERO global atomics: write base = bofs[b] + cbM[me][b] (deterministic).
__global__ __launch_bounds__(256) void k_binscatter(const int* __restrict__ src,
                                                    const int* __restrict__ dst,
                                                    const int* __restrict__ cbM,
                                                    const int* __restrict__ bofs,
                                                    unsigned* __restrict__ sedge,
                                                    int E, int nbuck) {
    __shared__ int hist[MAXB];
    __shared__ int lofs[MAXB];
    __shared__ int dlt[MAXB];       // (bofs[b] + cbM[me][b]) - lofs[b]
    __shared__ int ps[256];
    __shared__ uint2 stg[CHUNK];
    int t = threadIdx.x;
    int me = blockIdx.x;
    int e0 = me * CHUNK;
    int n = min(CHUNK, E - e0);

    int d[EPT], sv[EPT], rk[EPT];
#pragma unroll
    for (int u = 0; u < EPT; ++u) {
        int k = t + u * 256;
        d[u]  = (k < n) ? dst[e0 + k] : -1;
        sv[u] = (k < n) ? src[e0 + k] : 0;
    }
    for (int i = t; i < MAXB; i += 256) hist[i] = 0;
    __syncthreads();
#pragma unroll
    for (int u = 0; u < EPT; ++u)
        if (d[u] >= 0) rk[u] = atomicAdd(&hist[d[u] >> NPB_BITS], 1);
    __syncthreads();

    // block exclusive scan of hist (512 entries, 2 per thread)
    int base = t * 2;
    int h0 = hist[base], h1 = hist[base + 1];
    int s = h0 + h1;
    ps[t] = s;
    __syncthreads();
    for (int off = 1; off < 256; off <<= 1) {
        int a = (t >= off) ? ps[t - off] : 0;
        __syncthreads();
        ps[t] += a;
        __syncthreads();
    }
    int excl = ps[t] - s;
    lofs[base] = excl;
    lofs[base + 1] = excl + h0;
    __syncthreads();
    for (int i = t; i < nbuck; i += 256)
        dlt[i] = bofs[i] + cbM[me * MAXB + i] - lofs[i];
    __syncthreads();

    // place into bucket-major staging at r = lofs[b] + rank; addr fused in .y
#pragma unroll
    for (int u = 0; u < EPT; ++u) {
        if (d[u] < 0) continue;
        int b = d[u] >> NPB_BITS;
        int r = lofs[b] + rk[u];
        stg[r] = make_uint2(((unsigned)sv[u] << NPB_BITS) | (unsigned)(d[u] & (NPB - 1)),
                            (unsigned)(dlt[b] + r));
    }
    __syncthreads();

    // write-out: stride-1 LDS read pair + store (depth-1 chain)
    for (int r = t; r < n; r += 256) {
        uint2 v = stg[r];
        sedge[v.y] = v.x;
    }
}

// ---- within-bucket: node histogram (LDS) -> rowptr + dinv + sorted csr ----
__global__ __launch_bounds__(256) void k_sortnode(const int* __restrict__ bofs,
                                                  const unsigned* __restrict__ sedge,
                                                  int* __restrict__ csr,
                                                  int* __restrict__ rowptr,
                                                  float* __restrict__ dinv, int N) {
    __shared__ int hist[256];
    __shared__ int ps[256];
    __shared__ int lcur[256];
    __shared__ int stage[SSTAGE];
    int b = blockIdx.x, t = threadIdx.x;
    int base = bofs[b];
    int n = bofs[b + 1] - base;
    hist[t] = 0;
    __syncthreads();
    for (int k = t; k < n; k += 256)
        atomicAdd(&hist[sedge[base + k] & (NPB - 1)], 1);
    __syncthreads();
    int c = hist[t];
    ps[t] = c;
    __syncthreads();
    for (int off = 1; off < 256; off <<= 1) {
        int a = (t >= off) ? ps[t - off] : 0;
        __syncthreads();
        ps[t] += a;
        __syncthreads();
    }
    int excl = ps[t] - c;
    int node = b * NPB + t;
    if (node < N) {
        rowptr[node] = base + excl;
        dinv[node] = rsqrtf((float)c + 1.0f);
    }
    lcur[t] = excl;
    __syncthreads();
    bool staged = (n <= SSTAGE);
    for (int k = t; k < n; k += 256) {
        unsigned p = sedge[base + k];
        int d = p & (NPB - 1);
        int pos = atomicAdd(&lcur[d], 1);
        int sv = (int)(p >> NPB_BITS);
        if (staged) stage[pos] = sv;
        else        csr[base + pos] = sv;
    }
    __syncthreads();
    if (staged) {
        for (int k = t; k < n; k += 256) csr[base + k] = stage[k];
    }
}

// ---- g1 = bf16((x @ W1) * dinv[row]) ----
// 4 lanes per row (col-quad each), 2 rows per thread (r and r+64: same
// alignment phase). One W1 ds_read_b128 per k feeds 8 FMAs -> DS traffic
// halved vs 1-row/thread. x float4 loads are 4-lane-merged (16 lines/wave).
#define FMA2(va, vb, kk)                                                \
    {                                                                   \
        float4 w = *(const float4*)(ws + (kk) * HID + c4);              \
        aA.x = fmaf((va), w.x, aA.x); aA.y = fmaf((va), w.y, aA.y);     \
        aA.z = fmaf((va), w.z, aA.z); aA.w = fmaf((va), w.w, aA.w);     \
        aB.x = fmaf((vb), w.x, aB.x); aB.y = fmaf((vb), w.y, aB.y);     \
        aB.z = fmaf((vb), w.z, aB.z); aB.w = fmaf((vb), w.w, aB.w);     \
    }

__global__ __launch_bounds__(256) void k_gemm1(const float* __restrict__ x,
                                               const float* __restrict__ W1,
                                               const float* __restrict__ dinv,
                                               unsigned* __restrict__ g1, int N) {
    __shared__ float ws[F_IN * HID];   // 10.5 KB
    int t = threadIdx.x;
    {
        const float4* w4 = (const float4*)W1;
        float4* s4 = (float4*)ws;
#pragma unroll
        for (int u = 0; u < 3; ++u) {
            int i = t + u * 256;
            if (i < (F_IN * HID) / 4) s4[i] = w4[i];
        }
    }
    __syncthreads();
    int tr = t >> 2;                    // row slot 0..63
    int c4 = (t & 3) << 2;              // col quad
    int rA = blockIdx.x * 128 + tr;
    int rB = rA + 64;
    if (rA >= N) return;
    bool hasB = (rB < N);
    const float* xa = x + (long long)rA * F_IN;
    const float* xb = hasB ? (x + (long long)rB * F_IN) : xa;
    float4 aA = make_float4(0.f, 0.f, 0.f, 0.f);
    float4 aB = make_float4(0.f, 0.f, 0.f, 0.f);

    int p = (4 - (rA & 3)) & 3;         // same phase for rB (64*165 % 4 == 0)
    for (int k = 0; k < p; ++k) { FMA2(xa[k], xb[k], k); }

    const float4* xa4 = (const float4*)(xa + p);
    const float4* xb4 = (const float4*)(xb + p);
    int n4 = (F_IN - p) >> 2;           // 40 or 41
    int q = 0;
    for (; q + 2 <= n4; q += 2) {
        float4 va0 = xa4[q], vb0 = xb4[q];
        float4 va1 = xa4[q + 1], vb1 = xb4[q + 1];
        int kb = p + q * 4;
        FMA2(va0.x, vb0.x, kb + 0)
        FMA2(va0.y, vb0.y, kb + 1)
        FMA2(va0.z, vb0.z, kb + 2)
        FMA2(va0.w, vb0.w, kb + 3)
        FMA2(va1.x, vb1.x, kb + 4)
        FMA2(va1.y, vb1.y, kb + 5)
        FMA2(va1.z, vb1.z, kb + 6)
        FMA2(va1.w, vb1.w, kb + 7)
    }
    for (; q < n4; ++q) {
        float4 va = xa4[q], vb = xb4[q];
        int kb = p + q * 4;
        FMA2(va.x, vb.x, kb + 0)
        FMA2(va.y, vb.y, kb + 1)
        FMA2(va.z, vb.z, kb + 2)
        FMA2(va.w, vb.w, kb + 3)
    }
    for (int k = p + n4 * 4; k < F_IN; ++k) { FMA2(xa[k], xb[k], k); }

    float dA = dinv[rA];
    *(uint2*)(g1 + (long long)rA * 8 + (t & 3) * 2) =
        make_uint2(pk_bf16(aA.x * dA, aA.y * dA), pk_bf16(aA.z * dA, aA.w * dA));
    if (hasB) {
        float dB = dinv[rB];
        *(uint2*)(g1 + (long long)rB * 8 + (t & 3) * 2) =
            make_uint2(pk_bf16(aB.x * dB, aB.y * dB), pk_bf16(aB.z * dB, aB.w * dB));
    }
}

// ---- layer-1 CSR gather (bf16 rows), fp32 accum, fused bias/relu/W2 -> g2 ----
__global__ __launch_bounds__(256) void k_agg1(const int* __restrict__ rowptr,
                                              const int* __restrict__ csr,
                                              const unsigned* __restrict__ g1,
                                              const float* __restrict__ dinv,
                                              const float* __restrict__ b1,
                                              const float* __restrict__ W2,
                                              float* __restrict__ g2, int N) {
    int gid = blockIdx.x * 256 + threadIdx.x;
    int i = gid >> 3;
    int j = gid & 7;
    if (i >= N) return;
    int e0 = rowptr[i], e1 = rowptr[i + 1];
    unsigned w0 = g1[i * 8 + j];           // self-loop term
    float a0 = BF_LO(w0), a1 = BF_HI(w0);
    int e = e0;
    for (; e + 8 <= e1; e += 8) {
        int s0 = csr[e],     s1 = csr[e + 1], s2 = csr[e + 2], s3 = csr[e + 3];
        int s4 = csr[e + 4], s5 = csr[e + 5], s6 = csr[e + 6], s7 = csr[e + 7];
        unsigned u0 = g1[s0 * 8 + j], u1 = g1[s1 * 8 + j];
        unsigned u2 = g1[s2 * 8 + j], u3 = g1[s3 * 8 + j];
        unsigned u4 = g1[s4 * 8 + j], u5 = g1[s5 * 8 + j];
        unsigned u6 = g1[s6 * 8 + j], u7 = g1[s7 * 8 + j];
        a0 += ((BF_LO(u0) + BF_LO(u1)) + (BF_LO(u2) + BF_LO(u3))) +
              ((BF_LO(u4) + BF_LO(u5)) + (BF_LO(u6) + BF_LO(u7)));
        a1 += ((BF_HI(u0) + BF_HI(u1)) + (BF_HI(u2) + BF_HI(u3))) +
              ((BF_HI(u4) + BF_HI(u5)) + (BF_HI(u6) + BF_HI(u7)));
    }
    for (; e < e1; ++e) {
        unsigned u = g1[csr[e] * 8 + j];
        a0 += BF_LO(u);
        a1 += BF_HI(u);
    }
    float di = dinv[i];
    float v0 = fmaf(a0, di, b1[2 * j]);     v0 = v0 > 0.f ? v0 : 0.f;
    float v1 = fmaf(a1, di, b1[2 * j + 1]); v1 = v1 > 0.f ? v1 : 0.f;
    float4 w = ((const float4*)W2)[j];      // W2[2j][0..1], W2[2j+1][0..1]
    float c0 = fmaf(v1, w.z, v0 * w.x);
    float c1 = fmaf(v1, w.w, v0 * w.y);
    for (int off = 4; off; off >>= 1) {
        c0 += __shfl_xor(c0, off, 8);
        c1 += __shfl_xor(c1, off, 8);
    }
    if (j == 0) ((float2*)g2)[i] = make_float2(c0 * di, c1 * di);
}

// ---- layer-2 CSR gather + fused log_softmax -> out (4 lanes/node) ----
__global__ __launch_bounds__(256) void k_agg2(const int* __restrict__ rowptr,
                                              const int* __restrict__ csr,
                                              const float* __restrict__ g2,
                                              const float* __restrict__ dinv,
                                              const float* __restrict__ b2,
                                              float* __restrict__ out, int N) {
    int gid = blockIdx.x * 256 + threadIdx.x;
    int i = gid >> 2;
    int l = gid & 3;
    if (i >= N) return;
    int e0 = rowptr[i], e1 = rowptr[i + 1];
    float a0 = 0.f, a1 = 0.f;
    int e = e0 + l;
    for (; e + 4 < e1; e += 8) {
        int s0 = csr[e], s1 = csr[e + 4];
        float2 u = ((const float2*)g2)[s0];
        float2 w = ((const float2*)g2)[s1];
        a0 += u.x + w.x;
        a1 += u.y + w.y;
    }
    for (; e < e1; e += 4) {
        int s = csr[e];
        float2 u = ((const float2*)g2)[s];
        a0 += u.x;
        a1 += u.y;
    }
    a0 += __shfl_xor(a0, 1, 4); a0 += __shfl_xor(a0, 2, 4);
    a1 += __shfl_xor(a1, 1, 4); a1 += __shfl_xor(a1, 2, 4);
    if (l == 0) {
        float2 self = ((const float2*)g2)[i];
        float di = dinv[i];
        float A = fmaf(a0 + self.x, di, b2[0]);
        float B = fmaf(a1 + self.y, di, b2[1]);
        float m = fmaxf(A, B);
        float lse = m + logf(expf(A - m) + expf(B - m));
        ((float2*)out)[i] = make_float2(A - lse, B - lse);
    }
}

extern "C" void kernel_launch(void* const* d_in, const int* in_sizes, int n_in,
                              void* d_out, int out_size, void* d_ws, size_t ws_size,
                              hipStream_t stream) {
    const float* x  = (const float*)d_in[0];
    const int*   ei = (const int*)d_in[1];
    const float* W1 = (const float*)d_in[2];
    const float* b1 = (const float*)d_in[3];
    const float* W2 = (const float*)d_in[4];
    const float* b2 = (const float*)d_in[5];
    float* out = (float*)d_out;

    int N = in_sizes[0] / F_IN;
    int E = in_sizes[1] / 2;
    const int* src = ei;
    const int* dst = ei + E;
    int nbuck = (N + NPB - 1) >> NPB_BITS;
    int NB = (E + CHUNK - 1) / CHUNK;

    int* cbM      = (int*)d_ws;                     // NB*MAXB (counts -> excl offsets)
    int* btot     = cbM + (long long)NB * MAXB;     // MAXB
    int* bofs     = btot + MAXB;                    // MAXB+1
    int* rowptr   = bofs + MAXB + 1;                // N+1
    unsigned* sedge = (unsigned*)(rowptr + N + 1);  // E
    int* csr      = (int*)(sedge + E);              // E
    float* dinv   = (float*)(csr + E);              // N
    unsigned* g1  = (unsigned*)(dinv + N);          // 8N (bf16 rows)
    float* g2     = (float*)(g1 + (long long)8 * N);// 2N

    k_cnt<<<NB, 256, 0, stream>>>(dst, cbM, E);
    k_colscan<<<nbuck, 256, 0, stream>>>(cbM, btot, NB);
    k_bscan<<<1, 256, 0, stream>>>(btot, bofs, rowptr, nbuck, N);
    k_binscatter<<<NB, 256, 0, stream>>>(src, dst, cbM, bofs, sedge, E, nbuck);
    k_sortnode<<<nbuck, 256, 0, stream>>>(bofs, sedge, csr, rowptr, dinv, N);

    k_gemm1<<<(N + 127) / 128, 256, 0, stream>>>(x, W1, dinv, g1, N);

    k_agg1<<<(N * 8 + 255) / 256, 256, 0, stream>>>(rowptr, csr, g1, dinv, b1, W2, g2, N);
    k_agg2<<<(N * 4 + 255) / 256, 256, 0, stream>>>(rowptr, csr, g2, dinv, b2, out, N);
}